// Round 1
// baseline (237.196 us; speedup 1.0000x reference)
//
#include <hip/hip_runtime.h>
#include <math.h>

#define HH 384
#define WW 384
#define CNUM 64
#define BNUM 4
#define HWSZ (HH*WW)
#define NPLANES (BNUM*CNUM)              // 256
#define ROWS_PER_BLOCK 16
#define BLOCKS_PER_PLANE (HH/ROWS_PER_BLOCK)   // 24
#define NBLOCKS (NPLANES*BLOCKS_PER_PLANE)     // 6144
#define EPSBN 1e-5f

// compute raw pcm13 / pcm17 for one element (h,w) of plane pp
__device__ __forceinline__ void pcm_pair(const float* __restrict__ pp, int h, int w,
      int wp13, int wm13, int wp17, int wm17, float& pcm13, float& pcm17)
{
  const float* r0 = pp + h*WW;
  const float d = r0[w];
  int hp13 = h+13; if (hp13 >= HH) hp13 -= HH;
  int hm13 = h-13; if (hm13 <  0 ) hm13 += HH;
  int hp17 = h+17; if (hp17 >= HH) hp17 -= HH;
  int hm17 = h-17; if (hm17 <  0 ) hm17 += HH;
  const float* rp13 = pp + hp13*WW;
  const float* rm13 = pp + hm13*WW;
  const float* rp17 = pp + hp17*WW;
  const float* rm17 = pp + hm17*WW;
  {
    float s1 = (rp13[wp13]-d)*(rm13[wm13]-d);
    float s2 = (rp13[w   ]-d)*(rm13[w   ]-d);
    float s3 = (rp13[wm13]-d)*(rm13[wp13]-d);
    float s4 = (r0  [wm13]-d)*(r0  [wp13]-d);
    pcm13 = fminf(fminf(s1,s2), fminf(s3,s4));
  }
  {
    float s1 = (rp17[wp17]-d)*(rm17[wm17]-d);
    float s2 = (rp17[w   ]-d)*(rm17[w   ]-d);
    float s3 = (rp17[wm17]-d)*(rm17[wp17]-d);
    float s4 = (r0  [wm17]-d)*(r0  [wp17]-d);
    pcm17 = fminf(fminf(s1,s2), fminf(s3,s4));
  }
}

// Pass A: raw pcm sums/sumsq per block (deterministic partials, no atomics)
__global__ __launch_bounds__(384) void passA_kernel(const float* __restrict__ cen,
                                                    float* __restrict__ partials)
{
  const int blk = blockIdx.x;
  const int p   = blk / BLOCKS_PER_PLANE;
  const int kb  = blk % BLOCKS_PER_PLANE;
  const int w   = threadIdx.x;               // 0..383
  const float* pp = cen + (size_t)p*HWSZ;

  int wp13 = w+13; if (wp13 >= WW) wp13 -= WW;
  int wm13 = w-13; if (wm13 <  0 ) wm13 += WW;
  int wp17 = w+17; if (wp17 >= WW) wp17 -= WW;
  int wm17 = w-17; if (wm17 <  0 ) wm17 += WW;

  float s13 = 0.f, q13 = 0.f, s17 = 0.f, q17 = 0.f;
  const int h0 = kb*ROWS_PER_BLOCK;
  for (int r = 0; r < ROWS_PER_BLOCK; ++r) {
    float p13, p17;
    pcm_pair(pp, h0+r, w, wp13, wm13, wp17, wm17, p13, p17);
    s13 += p13; q13 += p13*p13;
    s17 += p17; q17 += p17*p17;
  }
  // wave64 reduce
  for (int off = 32; off > 0; off >>= 1) {
    s13 += __shfl_down(s13, off);
    q13 += __shfl_down(q13, off);
    s17 += __shfl_down(s17, off);
    q17 += __shfl_down(q17, off);
  }
  __shared__ float red[6][4];
  const int wid = threadIdx.x >> 6;
  if ((threadIdx.x & 63) == 0) {
    red[wid][0] = s13; red[wid][1] = q13; red[wid][2] = s17; red[wid][3] = q17;
  }
  __syncthreads();
  if (threadIdx.x == 0) {
    float a=0.f,b=0.f,c=0.f,d=0.f;
    for (int i = 0; i < 6; ++i) { a+=red[i][0]; b+=red[i][1]; c+=red[i][2]; d+=red[i][3]; }
    float* q = partials + (size_t)blk*4;
    q[0]=a; q[1]=b; q[2]=c; q[3]=d;
  }
}

// in-block SE MLP helper: all 256 threads must call.
// p : LDS [256] pooled (BN'd) means, wei out: LDS [256]
__device__ void se_mlp(int t, const float* __restrict__ p,
    const float* __restrict__ w1, const float* __restrict__ b1,
    const float* __restrict__ g1, const float* __restrict__ be1,
    const float* __restrict__ w2, const float* __restrict__ b2,
    const float* __restrict__ g2, const float* __restrict__ be2,
    float* y1, float* sc, float* sh, float* wei)
{
  // y1 = w1 @ p + b1  : [4][32]
  if (t < 128) {
    const int b = t >> 5, o = t & 31;
    float acc = b1[o];
    const float* wr = w1 + o*64;
    const float* pr = p  + b*64;
    #pragma unroll
    for (int c = 0; c < 64; ++c) acc += wr[c]*pr[c];
    y1[t] = acc;
  }
  __syncthreads();
  // BN over batch (4) per o, then relu
  if (t < 32) {
    float a0=y1[t], a1=y1[32+t], a2=y1[64+t], a3=y1[96+t];
    float m = 0.25f*(a0+a1+a2+a3);
    float q = 0.25f*(a0*a0+a1*a1+a2*a2+a3*a3);
    float v = q - m*m;
    float s = g1[t]*rsqrtf(v + EPSBN);
    sc[t] = s; sh[t] = be1[t] - m*s;
  }
  __syncthreads();
  if (t < 128) {
    const int o = t & 31;
    y1[t] = fmaxf(y1[t]*sc[o] + sh[o], 0.0f);
  }
  __syncthreads();
  // y2 = w2 @ y1r + b2 : [4][64]  (store into wei as temp)
  {
    const int b = t >> 6, o2 = t & 63;
    float acc = b2[o2];
    const float* wr = w2 + o2*32;
    const float* yr = y1 + b*32;
    #pragma unroll
    for (int o = 0; o < 32; ++o) acc += wr[o]*yr[o];
    wei[t] = acc;
  }
  __syncthreads();
  if (t < 64) {
    float a0=wei[t], a1=wei[64+t], a2=wei[128+t], a3=wei[192+t];
    float m = 0.25f*(a0+a1+a2+a3);
    float q = 0.25f*(a0*a0+a1*a1+a2*a2+a3*a3);
    float v = q - m*m;
    float s = g2[t]*rsqrtf(v + EPSBN);
    sc[t] = s; sh[t] = be2[t] - m*s;
  }
  __syncthreads();
  {
    const int o2 = t & 63;
    float z = wei[t]*sc[o2] + sh[o2];
    wei[t] = 1.0f/(1.0f + expf(-z));
  }
  __syncthreads();
}

// Tiny kernel: reduce partials -> BN stats -> SE MLPs -> per-plane coefficients
__global__ __launch_bounds__(256) void se_kernel(
    const float* __restrict__ partials,
    const float* __restrict__ bn1_g, const float* __restrict__ bn1_b,
    const float* __restrict__ bn2_g, const float* __restrict__ bn2_b,
    const float* __restrict__ td_w1, const float* __restrict__ td_b1,
    const float* __restrict__ td_g1, const float* __restrict__ td_be1,
    const float* __restrict__ td_w2, const float* __restrict__ td_b2,
    const float* __restrict__ td_g2, const float* __restrict__ td_be2,
    const float* __restrict__ bu_w1, const float* __restrict__ bu_b1,
    const float* __restrict__ bu_g1, const float* __restrict__ bu_be1,
    const float* __restrict__ bu_w2, const float* __restrict__ bu_b2,
    const float* __restrict__ bu_g2, const float* __restrict__ bu_be2,
    float* __restrict__ coef)
{
  __shared__ float sum13[256], sq13[256], sum17[256], sq17[256];
  __shared__ float scale1[64], shift1[64], scale2[64], shift2[64];
  __shared__ float pm13[256], pm17[256];
  __shared__ float y1[128], sc[64], sh[64];
  __shared__ float tdw[256], buw[256];
  const int t = threadIdx.x;

  // 1. per-(b,c) totals
  {
    float a=0.f,b=0.f,c=0.f,d=0.f;
    for (int kb = 0; kb < BLOCKS_PER_PLANE; ++kb) {
      const float* q = partials + ((size_t)(t*BLOCKS_PER_PLANE + kb))*4;
      a += q[0]; b += q[1]; c += q[2]; d += q[3];
    }
    sum13[t]=a; sq13[t]=b; sum17[t]=c; sq17[t]=d;
  }
  __syncthreads();

  // 2. per-channel BN stats over (N,H,W)
  if (t < 64) {
    float s=0.f,q=0.f,s2=0.f,q2=0.f;
    for (int b = 0; b < 4; ++b) {
      s  += sum13[b*64+t]; q  += sq13[b*64+t];
      s2 += sum17[b*64+t]; q2 += sq17[b*64+t];
    }
    const float inv = 1.0f/(4.0f*HWSZ);
    float m1 = s*inv,  v1 = q*inv  - m1*m1;
    float c1 = bn1_g[t]*rsqrtf(v1 + EPSBN);
    scale1[t] = c1; shift1[t] = bn1_b[t] - m1*c1;
    float m2 = s2*inv, v2 = q2*inv - m2*m2;
    float c2 = bn2_g[t]*rsqrtf(v2 + EPSBN);
    scale2[t] = c2; shift2[t] = bn2_b[t] - m2*c2;
  }
  __syncthreads();

  // 3. pooled means of BN'd pcm per (b,c)
  {
    const int c = t & 63;
    pm13[t] = (sum13[t]*(1.0f/HWSZ))*scale1[c] + shift1[c];
    pm17[t] = (sum17[t]*(1.0f/HWSZ))*scale2[c] + shift2[c];
  }
  __syncthreads();

  // 4. topdown SE on pcm17, bottomup SE on pcm13
  se_mlp(t, pm17, td_w1, td_b1, td_g1, td_be1, td_w2, td_b2, td_g2, td_be2, y1, sc, sh, tdw);
  se_mlp(t, pm13, bu_w1, bu_b1, bu_g1, bu_be1, bu_w2, bu_b2, bu_g2, bu_be2, y1, sc, sh, buw);

  // 5. per-plane combine coefficients
  {
    const int c = t & 63;
    float A  = tdw[t]*scale1[c];
    float Bc = buw[t]*scale2[c];
    float Cc = tdw[t]*shift1[c] + buw[t]*shift2[c];
    coef[t*4+0] = A; coef[t*4+1] = Bc; coef[t*4+2] = Cc;
  }
}

// Pass B: recompute pcm, apply per-plane affine combine, write out
__global__ __launch_bounds__(384) void passB_kernel(const float* __restrict__ cen,
                                                    const float* __restrict__ coef,
                                                    float* __restrict__ out)
{
  const int blk = blockIdx.x;
  const int p   = blk / BLOCKS_PER_PLANE;
  const int kb  = blk % BLOCKS_PER_PLANE;
  const int w   = threadIdx.x;
  const float A  = coef[p*4+0];
  const float Bc = coef[p*4+1];
  const float Cc = coef[p*4+2];
  const float* pp = cen + (size_t)p*HWSZ;
  float* op = out + (size_t)p*HWSZ;

  int wp13 = w+13; if (wp13 >= WW) wp13 -= WW;
  int wm13 = w-13; if (wm13 <  0 ) wm13 += WW;
  int wp17 = w+17; if (wp17 >= WW) wp17 -= WW;
  int wm17 = w-17; if (wm17 <  0 ) wm17 += WW;

  const int h0 = kb*ROWS_PER_BLOCK;
  for (int r = 0; r < ROWS_PER_BLOCK; ++r) {
    const int h = h0 + r;
    float p13, p17;
    pcm_pair(pp, h, w, wp13, wm13, wp17, wm17, p13, p17);
    op[h*WW + w] = A*p13 + Bc*p17 + Cc;
  }
}

extern "C" void kernel_launch(void* const* d_in, const int* in_sizes, int n_in,
                              void* d_out, int out_size, void* d_ws, size_t ws_size,
                              hipStream_t stream) {
  const float* cen = (const float*)d_in[0];
  float* ws = (float*)d_ws;
  float* partials = ws;                       // NBLOCKS*4 floats = 98,304 floats
  float* coef     = ws + (size_t)NBLOCKS*4;   // 256*4 floats

  passA_kernel<<<NBLOCKS, 384, 0, stream>>>(cen, partials);
  se_kernel<<<1, 256, 0, stream>>>(partials,
      (const float*)d_in[1],  (const float*)d_in[2],  (const float*)d_in[3],  (const float*)d_in[4],
      (const float*)d_in[5],  (const float*)d_in[6],  (const float*)d_in[7],  (const float*)d_in[8],
      (const float*)d_in[9],  (const float*)d_in[10], (const float*)d_in[11], (const float*)d_in[12],
      (const float*)d_in[13], (const float*)d_in[14], (const float*)d_in[15], (const float*)d_in[16],
      (const float*)d_in[17], (const float*)d_in[18], (const float*)d_in[19], (const float*)d_in[20],
      coef);
  passB_kernel<<<NBLOCKS, 384, 0, stream>>>(cen, coef, (float*)d_out);
}

// Round 2
// 194.451 us; speedup vs baseline: 1.2198x; 1.2198x over previous
//
#include <hip/hip_runtime.h>
#include <math.h>

#define HH 384
#define WW 384
#define CNUM 64
#define BNUM 4
#define HWSZ (HH*WW)
#define NPLANES (BNUM*CNUM)              // 256
#define ROWS_PER_BLOCK 16
#define BLOCKS_PER_PLANE (HH/ROWS_PER_BLOCK)   // 24
#define NBLOCKS (NPLANES*BLOCKS_PER_PLANE)     // 6144
#define EPSBN 1e-5f

// ---- stencil split into loads (17 independent) then eval, for ILP ----
__device__ __forceinline__ void pcm_loads(const float* __restrict__ pp, int h, int w,
      int wp13, int wm13, int wp17, int wm17, float* v)
{
  int hp13 = h+13; if (hp13 >= HH) hp13 -= HH;
  int hm13 = h-13; if (hm13 <  0 ) hm13 += HH;
  int hp17 = h+17; if (hp17 >= HH) hp17 -= HH;
  int hm17 = h-17; if (hm17 <  0 ) hm17 += HH;
  const float* r0   = pp + h*WW;
  const float* rp13 = pp + hp13*WW;
  const float* rm13 = pp + hm13*WW;
  const float* rp17 = pp + hp17*WW;
  const float* rm17 = pp + hm17*WW;
  v[0]  = r0[w];
  v[1]  = rp13[wp13]; v[2]  = rm13[wm13];
  v[3]  = rp13[w];    v[4]  = rm13[w];
  v[5]  = rp13[wm13]; v[6]  = rm13[wp13];
  v[7]  = r0[wm13];   v[8]  = r0[wp13];
  v[9]  = rp17[wp17]; v[10] = rm17[wm17];
  v[11] = rp17[w];    v[12] = rm17[w];
  v[13] = rp17[wm17]; v[14] = rm17[wp17];
  v[15] = r0[wm17];   v[16] = r0[wp17];
}

__device__ __forceinline__ void pcm_eval(const float* v, float& p13, float& p17)
{
  const float d = v[0];
  {
    float s1 = (v[1]-d)*(v[2]-d);
    float s2 = (v[3]-d)*(v[4]-d);
    float s3 = (v[5]-d)*(v[6]-d);
    float s4 = (v[7]-d)*(v[8]-d);
    p13 = fminf(fminf(s1,s2), fminf(s3,s4));
  }
  {
    float s1 = (v[9] -d)*(v[10]-d);
    float s2 = (v[11]-d)*(v[12]-d);
    float s3 = (v[13]-d)*(v[14]-d);
    float s4 = (v[15]-d)*(v[16]-d);
    p17 = fminf(fminf(s1,s2), fminf(s3,s4));
  }
}

// XCD-aware chunked swizzle: NBLOCKS divisible by 8; all blocks of a plane
// land on one XCD so halo rows hit its L2.
__device__ __forceinline__ int swz_block() {
  return (blockIdx.x & 7)*(NBLOCKS/8) + (blockIdx.x >> 3);
}

// Pass A: raw pcm sums/sumsq per block (deterministic partials, no atomics)
__global__ __launch_bounds__(384) void passA_kernel(const float* __restrict__ cen,
                                                    float* __restrict__ partials)
{
  const int blk = swz_block();
  const int p   = blk / BLOCKS_PER_PLANE;
  const int kb  = blk % BLOCKS_PER_PLANE;
  const int w   = threadIdx.x;               // 0..383
  const float* pp = cen + (size_t)p*HWSZ;

  int wp13 = w+13; if (wp13 >= WW) wp13 -= WW;
  int wm13 = w-13; if (wm13 <  0 ) wm13 += WW;
  int wp17 = w+17; if (wp17 >= WW) wp17 -= WW;
  int wm17 = w-17; if (wm17 <  0 ) wm17 += WW;

  float s13 = 0.f, q13 = 0.f, s17 = 0.f, q17 = 0.f;
  const int h0 = kb*ROWS_PER_BLOCK;
  #pragma unroll 2
  for (int r = 0; r < ROWS_PER_BLOCK; r += 2) {
    float va[17], vb[17];
    pcm_loads(pp, h0+r,   w, wp13, wm13, wp17, wm17, va);
    pcm_loads(pp, h0+r+1, w, wp13, wm13, wp17, wm17, vb);
    float a13, a17, b13, b17;
    pcm_eval(va, a13, a17);
    pcm_eval(vb, b13, b17);
    s13 += a13 + b13; q13 += a13*a13 + b13*b13;
    s17 += a17 + b17; q17 += a17*a17 + b17*b17;
  }
  // wave64 reduce
  for (int off = 32; off > 0; off >>= 1) {
    s13 += __shfl_down(s13, off);
    q13 += __shfl_down(q13, off);
    s17 += __shfl_down(s17, off);
    q17 += __shfl_down(q17, off);
  }
  __shared__ float red[6][4];
  const int wid = threadIdx.x >> 6;
  if ((threadIdx.x & 63) == 0) {
    red[wid][0] = s13; red[wid][1] = q13; red[wid][2] = s17; red[wid][3] = q17;
  }
  __syncthreads();
  if (threadIdx.x == 0) {
    float a=0.f,b=0.f,c=0.f,d=0.f;
    for (int i = 0; i < 6; ++i) { a+=red[i][0]; b+=red[i][1]; c+=red[i][2]; d+=red[i][3]; }
    float* q = partials + (size_t)blk*4;
    q[0]=a; q[1]=b; q[2]=c; q[3]=d;
  }
}

// in-block SE MLP helper: all 256 threads must call.
__device__ void se_mlp(int t, const float* __restrict__ p,
    const float* __restrict__ w1, const float* __restrict__ b1,
    const float* __restrict__ g1, const float* __restrict__ be1,
    const float* __restrict__ w2, const float* __restrict__ b2,
    const float* __restrict__ g2, const float* __restrict__ be2,
    float* y1, float* sc, float* sh, float* wei)
{
  if (t < 128) {
    const int b = t >> 5, o = t & 31;
    float acc = b1[o];
    const float* wr = w1 + o*64;
    const float* pr = p  + b*64;
    #pragma unroll
    for (int c = 0; c < 64; ++c) acc += wr[c]*pr[c];
    y1[t] = acc;
  }
  __syncthreads();
  if (t < 32) {
    float a0=y1[t], a1=y1[32+t], a2=y1[64+t], a3=y1[96+t];
    float m = 0.25f*(a0+a1+a2+a3);
    float q = 0.25f*(a0*a0+a1*a1+a2*a2+a3*a3);
    float v = q - m*m;
    float s = g1[t]*rsqrtf(v + EPSBN);
    sc[t] = s; sh[t] = be1[t] - m*s;
  }
  __syncthreads();
  if (t < 128) {
    const int o = t & 31;
    y1[t] = fmaxf(y1[t]*sc[o] + sh[o], 0.0f);
  }
  __syncthreads();
  {
    const int b = t >> 6, o2 = t & 63;
    float acc = b2[o2];
    const float* wr = w2 + o2*32;
    const float* yr = y1 + b*32;
    #pragma unroll
    for (int o = 0; o < 32; ++o) acc += wr[o]*yr[o];
    wei[t] = acc;
  }
  __syncthreads();
  if (t < 64) {
    float a0=wei[t], a1=wei[64+t], a2=wei[128+t], a3=wei[192+t];
    float m = 0.25f*(a0+a1+a2+a3);
    float q = 0.25f*(a0*a0+a1*a1+a2*a2+a3*a3);
    float v = q - m*m;
    float s = g2[t]*rsqrtf(v + EPSBN);
    sc[t] = s; sh[t] = be2[t] - m*s;
  }
  __syncthreads();
  {
    const int o2 = t & 63;
    float z = wei[t]*sc[o2] + sh[o2];
    wei[t] = 1.0f/(1.0f + expf(-z));
  }
  __syncthreads();
}

// Tiny kernel: reduce partials -> BN stats -> SE MLPs -> per-plane coefficients
__global__ __launch_bounds__(256) void se_kernel(
    const float* __restrict__ partials,
    const float* __restrict__ bn1_g, const float* __restrict__ bn1_b,
    const float* __restrict__ bn2_g, const float* __restrict__ bn2_b,
    const float* __restrict__ td_w1, const float* __restrict__ td_b1,
    const float* __restrict__ td_g1, const float* __restrict__ td_be1,
    const float* __restrict__ td_w2, const float* __restrict__ td_b2,
    const float* __restrict__ td_g2, const float* __restrict__ td_be2,
    const float* __restrict__ bu_w1, const float* __restrict__ bu_b1,
    const float* __restrict__ bu_g1, const float* __restrict__ bu_be1,
    const float* __restrict__ bu_w2, const float* __restrict__ bu_b2,
    const float* __restrict__ bu_g2, const float* __restrict__ bu_be2,
    float* __restrict__ coef)
{
  __shared__ float sum13[256], sq13[256], sum17[256], sq17[256];
  __shared__ float scale1[64], shift1[64], scale2[64], shift2[64];
  __shared__ float pm13[256], pm17[256];
  __shared__ float y1[128], sc[64], sh[64];
  __shared__ float tdw[256], buw[256];
  const int t = threadIdx.x;

  {
    float a=0.f,b=0.f,c=0.f,d=0.f;
    for (int kb = 0; kb < BLOCKS_PER_PLANE; ++kb) {
      const float* q = partials + ((size_t)(t*BLOCKS_PER_PLANE + kb))*4;
      a += q[0]; b += q[1]; c += q[2]; d += q[3];
    }
    sum13[t]=a; sq13[t]=b; sum17[t]=c; sq17[t]=d;
  }
  __syncthreads();

  if (t < 64) {
    float s=0.f,q=0.f,s2=0.f,q2=0.f;
    for (int b = 0; b < 4; ++b) {
      s  += sum13[b*64+t]; q  += sq13[b*64+t];
      s2 += sum17[b*64+t]; q2 += sq17[b*64+t];
    }
    const float inv = 1.0f/(4.0f*HWSZ);
    float m1 = s*inv,  v1 = q*inv  - m1*m1;
    float c1 = bn1_g[t]*rsqrtf(v1 + EPSBN);
    scale1[t] = c1; shift1[t] = bn1_b[t] - m1*c1;
    float m2 = s2*inv, v2 = q2*inv - m2*m2;
    float c2 = bn2_g[t]*rsqrtf(v2 + EPSBN);
    scale2[t] = c2; shift2[t] = bn2_b[t] - m2*c2;
  }
  __syncthreads();

  {
    const int c = t & 63;
    pm13[t] = (sum13[t]*(1.0f/HWSZ))*scale1[c] + shift1[c];
    pm17[t] = (sum17[t]*(1.0f/HWSZ))*scale2[c] + shift2[c];
  }
  __syncthreads();

  se_mlp(t, pm17, td_w1, td_b1, td_g1, td_be1, td_w2, td_b2, td_g2, td_be2, y1, sc, sh, tdw);
  se_mlp(t, pm13, bu_w1, bu_b1, bu_g1, bu_be1, bu_w2, bu_b2, bu_g2, bu_be2, y1, sc, sh, buw);

  {
    const int c = t & 63;
    float A  = tdw[t]*scale1[c];
    float Bc = buw[t]*scale2[c];
    float Cc = tdw[t]*shift1[c] + buw[t]*shift2[c];
    coef[t*4+0] = A; coef[t*4+1] = Bc; coef[t*4+2] = Cc;
  }
}

// Pass B: recompute pcm, apply per-plane affine combine, write out (nontemporal)
__global__ __launch_bounds__(384) void passB_kernel(const float* __restrict__ cen,
                                                    const float* __restrict__ coef,
                                                    float* __restrict__ out)
{
  const int blk = swz_block();
  const int p   = blk / BLOCKS_PER_PLANE;
  const int kb  = blk % BLOCKS_PER_PLANE;
  const int w   = threadIdx.x;
  const float A  = coef[p*4+0];
  const float Bc = coef[p*4+1];
  const float Cc = coef[p*4+2];
  const float* pp = cen + (size_t)p*HWSZ;
  float* op = out + (size_t)p*HWSZ;

  int wp13 = w+13; if (wp13 >= WW) wp13 -= WW;
  int wm13 = w-13; if (wm13 <  0 ) wm13 += WW;
  int wp17 = w+17; if (wp17 >= WW) wp17 -= WW;
  int wm17 = w-17; if (wm17 <  0 ) wm17 += WW;

  const int h0 = kb*ROWS_PER_BLOCK;
  #pragma unroll 2
  for (int r = 0; r < ROWS_PER_BLOCK; r += 2) {
    const int h = h0 + r;
    float va[17], vb[17];
    pcm_loads(pp, h,   w, wp13, wm13, wp17, wm17, va);
    pcm_loads(pp, h+1, w, wp13, wm13, wp17, wm17, vb);
    float a13, a17, b13, b17;
    pcm_eval(va, a13, a17);
    pcm_eval(vb, b13, b17);
    __builtin_nontemporal_store(A*a13 + Bc*a17 + Cc, &op[h*WW + w]);
    __builtin_nontemporal_store(A*b13 + Bc*b17 + Cc, &op[(h+1)*WW + w]);
  }
}

extern "C" void kernel_launch(void* const* d_in, const int* in_sizes, int n_in,
                              void* d_out, int out_size, void* d_ws, size_t ws_size,
                              hipStream_t stream) {
  const float* cen = (const float*)d_in[0];
  float* ws = (float*)d_ws;
  float* partials = ws;                       // NBLOCKS*4 floats
  float* coef     = ws + (size_t)NBLOCKS*4;   // 256*4 floats

  passA_kernel<<<NBLOCKS, 384, 0, stream>>>(cen, partials);
  se_kernel<<<1, 256, 0, stream>>>(partials,
      (const float*)d_in[1],  (const float*)d_in[2],  (const float*)d_in[3],  (const float*)d_in[4],
      (const float*)d_in[5],  (const float*)d_in[6],  (const float*)d_in[7],  (const float*)d_in[8],
      (const float*)d_in[9],  (const float*)d_in[10], (const float*)d_in[11], (const float*)d_in[12],
      (const float*)d_in[13], (const float*)d_in[14], (const float*)d_in[15], (const float*)d_in[16],
      (const float*)d_in[17], (const float*)d_in[18], (const float*)d_in[19], (const float*)d_in[20],
      coef);
  passB_kernel<<<NBLOCKS, 384, 0, stream>>>(cen, coef, (float*)d_out);
}